// Round 1
// baseline (215.281 us; speedup 1.0000x reference)
//
#include <hip/hip_runtime.h>
#include <math.h>

// Problem: y = x @ ste_quantize(W)^T + bias
//   x: [32768,1024] f32, W: [1024,1024] f32, bias: [1024] f32, out: [32768,1024] f32
//
// Key structural fact: scaled = (w_row/||w_row||)*1.2 has coords ~N(0,0.0375^2);
// |coord| >= 0.5 never occurs (13-sigma), so q_d4 == 0 everywhere, both HNLQ
// levels give coset 0, and w_q == 0 exactly. Reference output == bias broadcast.
// We still compute the quantizer faithfully and branch on an on-device flag so
// the kernel is correct for ANY input, not just this seed.

#define SCALE 1.2f  // BETA(0.3) * D_LAT(4)

// Conway-Sloane nearest-point quantizer for D4. Matches jnp semantics:
// round-half-even (rintf), argmax takes FIRST max, mod-parity check.
__device__ inline void q_d4(const float x[4], float out[4]) {
    float f[4], delta[4];
    float fsum = 0.f;
    int idx = 0;
    float best = -1.f;
#pragma unroll
    for (int k = 0; k < 4; ++k) {
        f[k] = rintf(x[k]);          // round half to even, like jnp.round
        delta[k] = x[k] - f[k];
        fsum += f[k];
        float a = fabsf(delta[k]);
        if (a > best) { best = a; idx = k; }   // strict > -> first max wins
    }
#pragma unroll
    for (int k = 0; k < 4; ++k) out[k] = f[k];
    // parity of integer-valued float sum (fmodf sign irrelevant for !=0 test)
    if (fmodf(fsum, 2.0f) != 0.0f) {
        out[idx] += (delta[idx] >= 0.f) ? 1.f : -1.f;
    }
}

// One block per weight row: row norm -> HNLQ quantize/dequant -> wq, nz count.
__global__ __launch_bounds__(256) void quant_kernel(
        const float* __restrict__ w, float* __restrict__ wq,
        int* __restrict__ counts) {
    const int row = blockIdx.x;
    const float* wr = w + row * 1024;

    // sum of squares over the row (256 threads x 4 elems)
    float ss = 0.f;
    const int g = threadIdx.x;            // this thread's 4-group
    float4 v = ((const float4*)wr)[g];
    ss = v.x * v.x + v.y * v.y + v.z * v.z + v.w * v.w;
#pragma unroll
    for (int off = 32; off >= 1; off >>= 1) ss += __shfl_down(ss, off, 64);
    __shared__ float red[4];
    const int wid = threadIdx.x >> 6, lane = threadIdx.x & 63;
    if (lane == 0) red[wid] = ss;
    __syncthreads();
    __shared__ float s_norm;
    if (threadIdx.x == 0) s_norm = sqrtf(red[0] + red[1] + red[2] + red[3]);
    __syncthreads();
    const float norm = fmaxf(s_norm, 1e-8f);

    // HNLQ: 2 levels, q = 4
    float xt[4], xh[4] = {0.f, 0.f, 0.f, 0.f};
    xt[0] = v.x / norm * SCALE;
    xt[1] = v.y / norm * SCALE;
    xt[2] = v.z / norm * SCALE;
    xt[3] = v.w / norm * SCALE;
    float pw = 1.f;
#pragma unroll
    for (int m = 0; m < 2; ++m) {
        float qx[4], tmp[4], qq[4];
        q_d4(xt, qx);
#pragma unroll
        for (int k = 0; k < 4; ++k) tmp[k] = qx[k] * 0.25f;
        q_d4(tmp, qq);
#pragma unroll
        for (int k = 0; k < 4; ++k) {
            xh[k] += pw * (qx[k] - 4.f * qq[k]);   // coset representative
            xt[k] = qx[k] * 0.25f;                  // next-level input
        }
        pw *= 4.f;
    }

    const float invs = norm / SCALE;
    int nz = 0;
    float4 q4;
    q4.x = xh[0] * invs; q4.y = xh[1] * invs; q4.z = xh[2] * invs; q4.w = xh[3] * invs;
    if (q4.x != 0.f || q4.y != 0.f || q4.z != 0.f || q4.w != 0.f) nz = 1;
    ((float4*)(wq + row * 1024))[g] = q4;

    __shared__ int cnt;
    if (threadIdx.x == 0) cnt = 0;
    __syncthreads();
    unsigned long long b = __ballot(nz != 0);
    if (lane == 0 && b != 0ull) atomicAdd(&cnt, 1);
    __syncthreads();
    if (threadIdx.x == 0) counts[row] = cnt;
}

// Reduce per-row counts into one flag (ws is re-poisoned each call, so the
// flag must be recomputed; plain stores only, no init races).
__global__ void flag_kernel(const int* __restrict__ counts, int* __restrict__ flag) {
    __shared__ int s;
    if (threadIdx.x == 0) s = 0;
    __syncthreads();
    if (counts[threadIdx.x] != 0) atomicAdd(&s, 1);
    __syncthreads();
    if (threadIdx.x == 0) *flag = s;
}

// Output: if w_q == 0 (always, for this data) -> broadcast bias (pure write
// stream, HBM-write-bound). Else -> correct naive GEMM fallback.
__global__ __launch_bounds__(256) void out_kernel(
        const float* __restrict__ x, const float* __restrict__ wq,
        const float* __restrict__ bias, const int* __restrict__ flag,
        float* __restrict__ out) {
    __shared__ float sb[1024];
    for (int i = threadIdx.x; i < 1024; i += 256) sb[i] = bias[i];
    __syncthreads();

    if (*flag == 0) {
        // out[b,o] = bias[o]; float4 stores, grid-stride
        float4* out4 = (float4*)out;
        const int total4 = 32768 * 256;                 // 8,388,608 float4
        const int stride = gridDim.x * blockDim.x;
        const float4* sb4 = (const float4*)sb;
        for (int j = blockIdx.x * blockDim.x + threadIdx.x; j < total4; j += stride) {
            out4[j] = sb4[j & 255];
        }
    } else {
        // never taken for this input; correctness insurance only
        const int total = 32768 * 1024;
        const int stride = gridDim.x * blockDim.x;
        for (int i = blockIdx.x * blockDim.x + threadIdx.x; i < total; i += stride) {
            const int b = i >> 10, o = i & 1023;
            float acc = sb[o];
            const float* xr = x + b * 1024;
            const float* wr = wq + o * 1024;
            for (int k = 0; k < 1024; ++k) acc = fmaf(xr[k], wr[k], acc);
            out[i] = acc;
        }
    }
}

extern "C" void kernel_launch(void* const* d_in, const int* in_sizes, int n_in,
                              void* d_out, int out_size, void* d_ws, size_t ws_size,
                              hipStream_t stream) {
    const float* x    = (const float*)d_in[0];   // [32768,1024]
    const float* w    = (const float*)d_in[1];   // [1024,1024]
    const float* bias = (const float*)d_in[2];   // [1024]
    float* out = (float*)d_out;

    // workspace layout: wq (4 MB) | counts (4 KB) | flag (4 B)
    float* wq   = (float*)d_ws;
    int* counts = (int*)((char*)d_ws + (4u << 20));
    int* flag   = (int*)((char*)d_ws + (4u << 20) + 4096);

    quant_kernel<<<1024, 256, 0, stream>>>(w, wq, counts);
    flag_kernel<<<1, 1024, 0, stream>>>(counts, flag);
    out_kernel<<<2048, 256, 0, stream>>>(x, wq, bias, flag, out);
}

// Round 4
// 211.635 us; speedup vs baseline: 1.0172x; 1.0172x over previous
//
#include <hip/hip_runtime.h>
#include <math.h>

// y = x @ ste_quantize(W)^T + bias
//   x: [32768,1024] f32, W: [1024,1024] f32, bias: [1024] f32, out: [32768,1024] f32
//
// Structural fact (verified R1, absmax=0.0): scaled rows have coords
// ~N(0,0.0375^2); q_d4 rounds all to 0, both HNLQ levels give coset 0,
// w_q == 0 exactly, so out == bias broadcast. We still run the quantizer
// faithfully every call and branch on its result, so the kernel is correct
// for any input. Fast path = pure 134 MB write stream (HBM-write-bound).

#define SCALE 1.2f  // BETA(0.3) * D_LAT(4)

// Conway-Sloane D4 nearest-point quantizer; jnp semantics:
// round-half-even (rintf), FIRST argmax, parity check on rounded sum.
__device__ inline void q_d4(const float x[4], float out[4]) {
    float f[4], delta[4];
    float fsum = 0.f;
    int idx = 0;
    float best = -1.f;
#pragma unroll
    for (int k = 0; k < 4; ++k) {
        f[k] = rintf(x[k]);
        delta[k] = x[k] - f[k];
        fsum += f[k];
        float a = fabsf(delta[k]);
        if (a > best) { best = a; idx = k; }   // strict > : first max wins
    }
#pragma unroll
    for (int k = 0; k < 4; ++k) out[k] = f[k];
    if (fmodf(fsum, 2.0f) != 0.0f) {
        out[idx] += (delta[idx] >= 0.f) ? 1.f : -1.f;
    }
}

// Wave-per-row HNLQ: 256 blocks x 4 waves = 1024 rows. No LDS, no barriers,
// no atomics — pure shfl reduction for the row norm.
__global__ __launch_bounds__(256) void quant_kernel(
        const float* __restrict__ w, float* __restrict__ wq,
        int* __restrict__ counts) {
    const int wid  = threadIdx.x >> 6;
    const int lane = threadIdx.x & 63;
    const int row  = (blockIdx.x << 2) + wid;
    const float4* wr4 = (const float4*)(w + row * 1024);

    float4 v[4];
    float ss = 0.f;
#pragma unroll
    for (int k = 0; k < 4; ++k) {
        v[k] = wr4[lane + (k << 6)];           // coalesced: lane-major
        ss += v[k].x * v[k].x + v[k].y * v[k].y + v[k].z * v[k].z + v[k].w * v[k].w;
    }
#pragma unroll
    for (int off = 32; off >= 1; off >>= 1) ss += __shfl_down(ss, off, 64);
    const float norm = fmaxf(sqrtf(__shfl(ss, 0, 64)), 1e-8f);
    const float rs = SCALE / norm;             // into lattice domain
    const float invs = norm / SCALE;           // back out

    float4* wo4 = (float4*)(wq + row * 1024);
    int nz = 0;
#pragma unroll
    for (int k = 0; k < 4; ++k) {
        float xt[4] = { v[k].x * rs, v[k].y * rs, v[k].z * rs, v[k].w * rs };
        float xh[4] = { 0.f, 0.f, 0.f, 0.f };
        float pw = 1.f;
#pragma unroll
        for (int m = 0; m < 2; ++m) {          // M_LEVELS=2, q=4
            float qx[4], tmp[4], qq[4];
            q_d4(xt, qx);
#pragma unroll
            for (int t = 0; t < 4; ++t) tmp[t] = qx[t] * 0.25f;
            q_d4(tmp, qq);
#pragma unroll
            for (int t = 0; t < 4; ++t) {
                xh[t] += pw * (qx[t] - 4.f * qq[t]);
                xt[t] = qx[t] * 0.25f;
            }
            pw *= 4.f;
        }
        float4 q4;
        q4.x = xh[0] * invs; q4.y = xh[1] * invs;
        q4.z = xh[2] * invs; q4.w = xh[3] * invs;
        if (q4.x != 0.f || q4.y != 0.f || q4.z != 0.f || q4.w != 0.f) nz = 1;
        wo4[lane + (k << 6)] = q4;
    }

    unsigned long long b = __ballot(nz != 0);
    if (lane == 0) counts[row] = (b != 0ull) ? 1 : 0;   // plain store, no init needed
}

// Output writer. Each block re-derives the global flag from the 1024 per-row
// counts (4 KB, L2-hit, overlapped across blocks) — no separate flag kernel,
// no extra serialization point. Fast path: pure float4 write stream.
__global__ __launch_bounds__(256) void out_kernel(
        const float* __restrict__ x, const float* __restrict__ wq,
        const float* __restrict__ bias, const int* __restrict__ counts,
        float* __restrict__ out) {
    const int tid = threadIdx.x;
    const int wid = tid >> 6, lane = tid & 63;

    int nz = counts[tid] | counts[tid + 256] | counts[tid + 512] | counts[tid + 768];
    unsigned long long b = __ballot(nz != 0);
    __shared__ int wf[4];
    if (lane == 0) wf[wid] = (b != 0ull) ? 1 : 0;
    __syncthreads();
    const int flag = wf[0] | wf[1] | wf[2] | wf[3];

    if (flag == 0) {
        // out[b, o] = bias[o].  With 256-thread blocks, j % 256 == tid for
        // every j this thread touches -> its 4 output columns are fixed.
        const float4 bv = ((const float4*)bias)[tid];
        float4* out4 = (float4*)out;
        const int total4 = 32768 * 256;
        const int stride = gridDim.x * blockDim.x;
        for (int j = blockIdx.x * blockDim.x + tid; j < total4; j += stride) {
            out4[j] = bv;
        }
    } else {
        // Correctness insurance only (never taken for this data).
        const int total = 32768 * 1024;
        const int stride = gridDim.x * blockDim.x;
        for (int i = blockIdx.x * blockDim.x + tid; i < total; i += stride) {
            const int bb = i >> 10, o = i & 1023;
            float acc = bias[o];
            const float* xr = x + bb * 1024;
            const float* wr = wq + o * 1024;
            for (int k = 0; k < 1024; ++k) acc = fmaf(xr[k], wr[k], acc);
            out[i] = acc;
        }
    }
}

extern "C" void kernel_launch(void* const* d_in, const int* in_sizes, int n_in,
                              void* d_out, int out_size, void* d_ws, size_t ws_size,
                              hipStream_t stream) {
    const float* x    = (const float*)d_in[0];   // [32768,1024]
    const float* w    = (const float*)d_in[1];   // [1024,1024]
    const float* bias = (const float*)d_in[2];   // [1024]
    float* out = (float*)d_out;

    // workspace: wq (4 MB) | counts (1024 ints)
    float* wq   = (float*)d_ws;
    int* counts = (int*)((char*)d_ws + (4u << 20));

    quant_kernel<<<256, 256, 0, stream>>>(w, wq, counts);
    out_kernel<<<2048, 256, 0, stream>>>(x, wq, bias, counts, out);
}